// Round 5
// baseline (144.224 us; speedup 1.0000x reference)
//
#include <hip/hip_runtime.h>

// Conv2D 15x15 valid, 4096^2 fp32 -> 4082^2 fp32, via bf16 MFMA Toeplitz-band.
//
// R5: BARRIER-FREE wave-autonomous tiles. Post-mortem R1/R2/R3/R4: every
// per-pipe lever (B-operand path, LDS volume, conflicts) left time at ~50us;
// no pipe >52%. Diagnosis: block-wide stage -> __syncthreads -> compute
// structure lockstep-idles LDS during staging and VMEM during compute
// (LDS duty 52% = compute-phase fraction). Fix: each wave stages its OWN
// 30 input rows (16 out + 14 halo) into wave-private LDS; no barrier at all.
// Wave phases interleave statistically -> pipes see a mix, latency hidden by
// 24+ independent waves/CU instead of 2-4 synced blocks.
//
// Cost: 120 staged rows/block vs 78 (+54%), but dup rows are L1-hits (block
// working set 25 KB fp32 < 32 KB L1) -> HBM FETCH ~flat. B via in-loop L1-hot
// dwordx4 (R1-proven free; keeps VGPR <= ~70 for concurrency).
// __launch_bounds__(256,6): 85-VGPR cap, no spill (watch WRITE_SIZE!), LDS
// 21.1 KB/block -> 6-7 blocks/CU.
//
// History (us/dispatch): R1 50 (B in-loop); R2 62 (32x32, B via L2 - bad);
// R3 80 (DPP -> spill); R4 50 (B in regs, = R1).

#define HIN 4096
#define WIN 4096
#define KH 15
#define KW 15
#define OH (HIN - KH + 1)  // 4082
#define OW (WIN - KW + 1)  // 4082

#define BX 64
#define BY 64
#define WROWS 30                // per-wave staged rows: 16 outputs + 14 halo
#define XCOLS 80                // staged input cols (64 + 14, padded to 80)
#define LDSW 88                 // bf16 row stride (176 B -> bank skew 12 dwords)
#define WSH (WROWS * LDSW)      // 2640 shorts per wave
#define NSH (4 * WSH)           // 10560 shorts = 21120 B LDS
#define WNB4 (XCOLS / 4)        // 20 float4 per staged row
#define WNITEM (WROWS * WNB4)   // 600 staging items per wave

typedef short bf16x8 __attribute__((ext_vector_type(8)));
typedef float f32x4  __attribute__((ext_vector_type(4)));

static __device__ inline short f2bf(float f) {  // fp32 -> bf16 RNE
    unsigned u = __float_as_uint(f);
    u += 0x7fffu + ((u >> 16) & 1u);
    return (short)(u >> 16);
}

// ---- prep: build B-fragment table (15 kh x 64 lanes x bf16x8) once in ws ----
// 16x16x32 B-operand layout: lane L holds B[k=(L>>4)*8+j][n=L&15], j=0..7,
// with B[k][n] = w[kh][k-n] (0 outside band).
__global__ void conv2d_btab(const float* __restrict__ w, short* __restrict__ btab) {
    const int e = blockIdx.x * 256 + threadIdx.x;
    if (e >= KH * 64) return;
    const int kh = e >> 6;
    const int L  = e & 63;
    const int n  = L & 15;
    const int q  = L >> 4;
    bf16x8 bv;
#pragma unroll
    for (int j = 0; j < 8; ++j) {
        const int d = q * 8 + j - n;          // k - n
        bv[j] = (d >= 0 && d < KW) ? f2bf(w[kh * KW + d]) : (short)0;
    }
    *reinterpret_cast<bf16x8*>(&btab[(size_t)e * 8]) = bv;
}

__global__ __launch_bounds__(256, 6)
void conv2d_mfma(const float* __restrict__ x,
                 const short* __restrict__ btab,
                 const float* __restrict__ bias,
                 float* __restrict__ out) {
    __shared__ short lds[NSH];

    const int tid  = threadIdx.x;
    const int lane = tid & 63;
    const int wv   = tid >> 6;           // wave id 0..3
    const int ox0  = blockIdx.x * BX;
    const int oy0  = blockIdx.y * BY;
    const int gy0  = oy0 + wv * 16;      // this wave's first input row

    short* wlds = &lds[wv * WSH];        // wave-private staging region

    // -------- stage this wave's x rows: 30 x 80 fp32 -> bf16 LDS (no barrier) --------
    if (ox0 + XCOLS <= WIN && gy0 + WROWS <= HIN) {
        // interior fast path: two 5-deep load batches, then convert+write
#pragma unroll
        for (int half = 0; half < 2; ++half) {
            float4 v[5];
#pragma unroll
            for (int i = 0; i < 5; ++i) {
                const int f = lane + 64 * (half * 5 + i);
                if (f < WNITEM) {
                    const int r  = f / WNB4;
                    const int c4 = (f - r * WNB4) * 4;
                    v[i] = *reinterpret_cast<const float4*>(&x[(size_t)(gy0 + r) * WIN + ox0 + c4]);
                }
            }
#pragma unroll
            for (int i = 0; i < 5; ++i) {
                const int f = lane + 64 * (half * 5 + i);
                if (f < WNITEM) {
                    const int r  = f / WNB4;
                    const int c4 = (f - r * WNB4) * 4;
                    short4 s;
                    s.x = f2bf(v[i].x); s.y = f2bf(v[i].y);
                    s.z = f2bf(v[i].z); s.w = f2bf(v[i].w);
                    *reinterpret_cast<short4*>(&wlds[r * LDSW + c4]) = s;  // ds_write_b64
                }
            }
        }
    } else {
        // edge waves: clamped per-item path (clamped data feeds only masked outputs)
        for (int f = lane; f < WNITEM; f += 64) {
            const int r  = f / WNB4;
            const int c4 = (f - r * WNB4) * 4;
            int gy = gy0 + r;
            if (gy > HIN - 1) gy = HIN - 1;
            const int gx = ox0 + c4;
            float4 v;
            if (gx + 3 <= WIN - 1) {
                v = *reinterpret_cast<const float4*>(&x[(size_t)gy * WIN + gx]);
            } else {
                const float* row = &x[(size_t)gy * WIN];
                const int x0 = (gx + 0 > WIN - 1) ? WIN - 1 : gx + 0;
                const int x1 = (gx + 1 > WIN - 1) ? WIN - 1 : gx + 1;
                const int x2 = (gx + 2 > WIN - 1) ? WIN - 1 : gx + 2;
                const int x3 = (gx + 3 > WIN - 1) ? WIN - 1 : gx + 3;
                v = make_float4(row[x0], row[x1], row[x2], row[x3]);
            }
            short4 s;
            s.x = f2bf(v.x); s.y = f2bf(v.y); s.z = f2bf(v.z); s.w = f2bf(v.w);
            *reinterpret_cast<short4*>(&wlds[r * LDSW + c4]) = s;
        }
    }

    // ---------------- compute: 15 kh x 4 x-tiles of 16x16 MFMA ----------------
    // No __syncthreads: this wave reads only its own region; compiler emits
    // lgkmcnt waits for the ds_write -> ds_read dependency automatically.
    const int m = lane & 15;       // A-row (and D-col) index
    const int q = lane >> 4;       // quad

    f32x4 acc[4];
#pragma unroll
    for (int t = 0; t < 4; ++t) acc[t] = (f32x4){0.f, 0.f, 0.f, 0.f};

    // A-frag base: wave-local row m, col q*8 (+ kh*LDSW + t*16, imm-friendly)
    const short*  abase = &wlds[m * LDSW + q * 8];
    const bf16x8* bt    = reinterpret_cast<const bf16x8*>(btab) + lane;
#pragma unroll
    for (int kh = 0; kh < KH; ++kh) {
        const bf16x8 b = bt[kh * 64];   // global dwordx4, L1-hot (15 KB table)
#pragma unroll
        for (int t = 0; t < 4; ++t) {
            const bf16x8 a =
                *reinterpret_cast<const bf16x8*>(abase + kh * LDSW + t * 16);  // ds_read_b128
            acc[t] = __builtin_amdgcn_mfma_f32_16x16x32_bf16(a, b, acc[t], 0, 0, 0);
        }
    }

    // ---------------- epilogue: D layout col=lane&15, row=q*4+reg ----------------
    const float b0 = bias[0];
    const int row0 = gy0 + q * 4;
#pragma unroll
    for (int t = 0; t < 4; ++t) {
        const int col = ox0 + t * 16 + m;
        if (col < OW) {
#pragma unroll
            for (int r = 0; r < 4; ++r) {
                const int row = row0 + r;
                if (row < OH)
                    out[(size_t)row * OW + col] = acc[t][r] + b0;
            }
        }
    }
}

extern "C" void kernel_launch(void* const* d_in, const int* in_sizes, int n_in,
                              void* d_out, int out_size, void* d_ws, size_t ws_size,
                              hipStream_t stream) {
    const float* x    = (const float*)d_in[0];
    const float* w    = (const float*)d_in[1];
    const float* bias = (const float*)d_in[2];
    float* out        = (float*)d_out;
    short* btab       = (short*)d_ws;   // 15*64*8 shorts = 15360 B

    conv2d_btab<<<dim3((KH * 64 + 255) / 256), dim3(256), 0, stream>>>(w, btab);

    dim3 grid((OW + BX - 1) / BX, (OH + BY - 1) / BY);  // 64 x 64
    dim3 block(256);
    conv2d_mfma<<<grid, block, 0, stream>>>(x, btab, bias, out);
}

// Round 7
// 142.181 us; speedup vs baseline: 1.0144x; 1.0144x over previous
//
#include <hip/hip_runtime.h>

// Conv2D 15x15 valid, 4096^2 fp32 -> 4082^2 fp32, via bf16 MFMA Toeplitz-band.
//
// R7: software-pipelined multi-tile blocks, DOUBLE-BUFFERED LDS.
// R6 (single-buffer rotate, sync-write-sync) failed the graph-replay
// determinism tripwire (post-timing absmax 23.6 vs 0.5) -- an LDS race in the
// read->overwrite rotation. Fix by construction: tile j lives in buf[j&1];
// writes always target the buffer NOT being read this iteration; one
// __syncthreads at end of iteration separates write(b) from both the
// preceding reads (iter j-1) and following reads (iter j+1) of that buffer.
//
// Pipeline (per block, 4 y-tiles): issue tile j+1's 7 float4 loads ->
// compute tile j (60 MFMA, ~2.5k cy hides the HBM latency) -> store ->
// cvt+ds_write tile j+1 -> barrier. 3 of 4 stage latencies hidden.
//
// Ledger (us/dispatch): R1 50 (B in-loop L1); R2 62 (B via L2: bad); R3 80
// (DPP->spill); R4 50 (B in 60 VGPRs == R1); R5 56 (barrier-free waves);
// R6 failed (race). Staging/B-path/epilogue here are byte-identical to the
// R1/R4/R5 lineage that passed.

#define HIN 4096
#define WIN 4096
#define KH 15
#define KW 15
#define OH (HIN - KH + 1)  // 4082
#define OW (WIN - KW + 1)  // 4082

#define BX 64
#define BY 64
#define XROWS (BY + KH - 1)     // 78 staged input rows
#define XCOLS 80                // staged input cols (64 + 14, padded to 80)
#define LDSW 88                 // bf16 row stride (176 B -> bank skew 12 dwords)
#define NSH (XROWS * LDSW)      // 6864 shorts = 13728 B per buffer
#define NB4 (XCOLS / 4)         // 20 float4 per staged row
#define NITEM (XROWS * NB4)     // 1560 staging items per block
#define TJ 4                    // y-tiles per block
#define GRIDY 16                // grid.y; tile stride in tile space

typedef short bf16x8 __attribute__((ext_vector_type(8)));
typedef float f32x4  __attribute__((ext_vector_type(4)));

static __device__ inline short f2bf(float f) {  // fp32 -> bf16 RNE
    unsigned u = __float_as_uint(f);
    u += 0x7fffu + ((u >> 16) & 1u);
    return (short)(u >> 16);
}

// ---- prep: build B-fragment table (15 kh x 64 lanes x bf16x8) once in ws ----
// 16x16x32 B-operand layout: lane L holds B[k=(L>>4)*8+j][n=L&15], j=0..7,
// with B[k][n] = w[kh][k-n] (0 outside band).
__global__ void conv2d_btab(const float* __restrict__ w, short* __restrict__ btab) {
    const int e = blockIdx.x * 256 + threadIdx.x;
    if (e >= KH * 64) return;
    const int kh = e >> 6;
    const int L  = e & 63;
    const int n  = L & 15;
    const int q  = L >> 4;
    bf16x8 bv;
#pragma unroll
    for (int j = 0; j < 8; ++j) {
        const int d = q * 8 + j - n;          // k - n
        bv[j] = (d >= 0 && d < KW) ? f2bf(w[kh * KW + d]) : (short)0;
    }
    *reinterpret_cast<bf16x8*>(&btab[(size_t)e * 8]) = bv;
}

__global__ __launch_bounds__(256, 4)
void conv2d_mfma(const float* __restrict__ x,
                 const short* __restrict__ btab,
                 const float* __restrict__ bias,
                 float* __restrict__ out) {
    __shared__ short lds[2][NSH];

    const int tid = threadIdx.x;
    const int ox0 = blockIdx.x * BX;
    const bool xedge = (ox0 + XCOLS > WIN);   // bx == 63

    // staging item indices (loop-invariant): item f = tid + 256*i
    int fr[7], fc[7];
#pragma unroll
    for (int i = 0; i < 7; ++i) {
        const int f = tid + 256 * i;
        fr[i] = f / NB4;
        fc[i] = (f - fr[i] * NB4) * 4;
    }
    const bool v6 = (tid + 256 * 6) < NITEM;   // only i=6 is partial (1560 = 6*256+24)

    float4 v[7];   // in-flight stage registers (28 VGPRs, live across compute)

    // issue a tile's global loads (no waiting; consumed by stage_write)
    auto stage_issue = [&](int iy0) {
        if (!xedge) {
#pragma unroll
            for (int i = 0; i < 7; ++i) {
                if (i < 6 || v6) {
                    int gy = iy0 + fr[i];
                    if (gy > HIN - 1) gy = HIN - 1;   // clamped rows feed masked outputs
                    v[i] = *reinterpret_cast<const float4*>(&x[(size_t)gy * WIN + ox0 + fc[i]]);
                }
            }
        } else {
#pragma unroll
            for (int i = 0; i < 7; ++i) {
                if (i < 6 || v6) {
                    int gy = iy0 + fr[i];
                    if (gy > HIN - 1) gy = HIN - 1;
                    const float* row = &x[(size_t)gy * WIN];
                    const int gx = ox0 + fc[i];
                    const int x0 = (gx + 0 > WIN - 1) ? WIN - 1 : gx + 0;
                    const int x1 = (gx + 1 > WIN - 1) ? WIN - 1 : gx + 1;
                    const int x2 = (gx + 2 > WIN - 1) ? WIN - 1 : gx + 2;
                    const int x3 = (gx + 3 > WIN - 1) ? WIN - 1 : gx + 3;
                    v[i] = make_float4(row[x0], row[x1], row[x2], row[x3]);
                }
            }
        }
    };
    // convert + write staged registers into LDS buffer (vmcnt wait lands here)
    auto stage_write = [&](short* buf) {
#pragma unroll
        for (int i = 0; i < 7; ++i) {
            if (i < 6 || v6) {
                short4 s;
                s.x = f2bf(v[i].x); s.y = f2bf(v[i].y);
                s.z = f2bf(v[i].z); s.w = f2bf(v[i].w);
                *reinterpret_cast<short4*>(&buf[fr[i] * LDSW + fc[i]]) = s;  // ds_write_b64
            }
        }
    };

    const int lane = tid & 63;
    const int wv   = tid >> 6;        // wave id 0..3 -> output rows [16*wv, +16)
    const int m    = lane & 15;       // A-row (and D-col) index
    const int q    = lane >> 4;       // quad

    const int     aoff = (wv * 16 + m) * LDSW + q * 8;   // A-frag base within a buffer
    const bf16x8* bt   = reinterpret_cast<const bf16x8*>(btab) + lane;
    const float   b0   = bias[0];

    // -------- prologue: stage tile 0 into buf0 (the one exposed stage latency) --------
    stage_issue(blockIdx.y * BY);
    stage_write(&lds[0][0]);
    __syncthreads();

#pragma unroll
    for (int j = 0; j < TJ; ++j) {
        const int oy0 = (blockIdx.y + GRIDY * j) * BY;

        // issue next tile's loads BEFORE compute: they fly under the MFMAs
        if (j + 1 < TJ)
            stage_issue((blockIdx.y + GRIDY * (j + 1)) * BY);

        // ---------------- compute: 15 kh x 4 x-tiles of 16x16 MFMA ----------------
        const short* abase = &lds[j & 1][0] + aoff;   // static buffer select (unrolled j)
        f32x4 acc[4];
#pragma unroll
        for (int t = 0; t < 4; ++t) acc[t] = (f32x4){0.f, 0.f, 0.f, 0.f};
#pragma unroll
        for (int kh = 0; kh < KH; ++kh) {
            const bf16x8 b = bt[kh * 64];   // global dwordx4, L1-hot (15 KB table)
#pragma unroll
            for (int t = 0; t < 4; ++t) {
                const bf16x8 a =
                    *reinterpret_cast<const bf16x8*>(abase + kh * LDSW + t * 16);  // ds_read_b128
                acc[t] = __builtin_amdgcn_mfma_f32_16x16x32_bf16(a, b, acc[t], 0, 0, 0);
            }
        }

        // ---------------- epilogue: D layout col=lane&15, row=q*4+reg ----------------
        const int row0 = oy0 + wv * 16 + q * 4;
#pragma unroll
        for (int t = 0; t < 4; ++t) {
            const int col = ox0 + t * 16 + m;
            if (col < OW) {
#pragma unroll
                for (int r = 0; r < 4; ++r) {
                    const int row = row0 + r;
                    if (row < OH)
                        out[(size_t)row * OW + col] = acc[t][r] + b0;   // fire-and-forget
                }
            }
        }

        // -------- write next tile into the OTHER buffer; one barrier per iter --------
        if (j + 1 < TJ) {
            stage_write(&lds[(j + 1) & 1][0]);  // nobody reads this buffer this iter
            __syncthreads();                    // separates write from iter j+1 reads
        }
    }
}

extern "C" void kernel_launch(void* const* d_in, const int* in_sizes, int n_in,
                              void* d_out, int out_size, void* d_ws, size_t ws_size,
                              hipStream_t stream) {
    const float* x    = (const float*)d_in[0];
    const float* w    = (const float*)d_in[1];
    const float* bias = (const float*)d_in[2];
    float* out        = (float*)d_out;
    short* btab       = (short*)d_ws;   // 15*64*8 shorts = 15360 B

    conv2d_btab<<<dim3((KH * 64 + 255) / 256), dim3(256), 0, stream>>>(w, btab);

    dim3 grid((OW + BX - 1) / BX, GRIDY);   // 64 x 16 blocks, 4 y-tiles each
    dim3 block(256);
    conv2d_mfma<<<grid, block, 0, stream>>>(x, btab, bias, out);
}

// Round 8
// 137.561 us; speedup vs baseline: 1.0484x; 1.0336x over previous
//
#include <hip/hip_runtime.h>

// Conv2D 15x15 valid, 4096^2 fp32 -> 4082^2 fp32, via bf16 MFMA Toeplitz-band.
//
// R8: register-resident A via DPP row-rotation -- R3 rerun WITHOUT the spill.
// R3's 80us was poisoned: __launch_bounds__(256,8)'s 64-VGPR cap spilled 16
// regs/thread (WRITE_SIZE 71.5->138 MB, +67 MB = exactly one 16-reg spill).
// Here (256,4) = 128-VGPR cap, est ~90 used, no spill (guard: WRITE_SIZE).
//
// Theory: every passing variant kept the same in-loop LDS A-stream
// (240 ds_read_b128/block) and all landed 50-57us with NO pipe >40% --
// conflicts (R2), LDS volume (R2), B-path (R4), barrier (R5), stage-latency
// (R7) all individually falsified. Surviving candidate: per-MFMA LDS
// round-trip latency (~120+cy) with only 2-4 waves/SIMD to hide it. Fix:
// A-frag(kh+1,t)[lane m] == A-frag(kh,t)[lane m+1] (window slides one row
// per kh); m-groups are DPP rows, so v_mov_b32_dpp row_shl:1 (2cy VALU)
// replaces the 1 KB ds_read_b128; only m==15 lanes refresh from LDS
// (exec-masked b128, 64 B). kh loop = 16 dpp + 1 L1 B-load + 4 MFMA.
//
// Ledger (us/dispatch): R1 50; R2 62 (B via L2); R3 80 (spill); R4 50
// (B in regs == R1); R5 56 (barrier-free); R6 race; R7 57 (pipelined).

#define HIN 4096
#define WIN 4096
#define KH 15
#define KW 15
#define OH (HIN - KH + 1)  // 4082
#define OW (WIN - KW + 1)  // 4082

#define BX 64
#define BY 64
#define XROWS (BY + KH - 1)     // 78 staged input rows
#define XCOLS 80                // staged input cols (64 + 14, padded to 80)
#define LDSW 88                 // bf16 row stride (176 B -> bank skew 12 dwords)
#define NSH (XROWS * LDSW)      // 6864 shorts = 13728 B LDS
#define NB4 (XCOLS / 4)         // 20 float4 per staged row
#define NITEM (XROWS * NB4)     // 1560 staging items per block

typedef short bf16x8 __attribute__((ext_vector_type(8)));
typedef int   i32x4  __attribute__((ext_vector_type(4)));
typedef float f32x4  __attribute__((ext_vector_type(4)));

static __device__ inline short f2bf(float f) {  // fp32 -> bf16 RNE
    unsigned u = __float_as_uint(f);
    u += 0x7fffu + ((u >> 16) & 1u);
    return (short)(u >> 16);
}

// DPP row_shl:1 (ctrl 0x101): within each 16-lane row, lane i <- lane i+1.
// Lane 15 of each row has no source (bound_ctrl=false) -> gets old=0;
// caller overwrites those lanes from LDS.
static __device__ inline bf16x8 rot_up(bf16x8 f) {
    i32x4 fi = __builtin_bit_cast(i32x4, f);
#pragma unroll
    for (int d = 0; d < 4; ++d)
        fi[d] = __builtin_amdgcn_update_dpp(0, fi[d], 0x101, 0xf, 0xf, false);
    return __builtin_bit_cast(bf16x8, fi);
}

// ---- prep: build B-fragment table (15 kh x 64 lanes x bf16x8) once in ws ----
// 16x16x32 B-operand layout: lane L holds B[k=(L>>4)*8+j][n=L&15], j=0..7,
// with B[k][n] = w[kh][k-n] (0 outside band).
__global__ void conv2d_btab(const float* __restrict__ w, short* __restrict__ btab) {
    const int e = blockIdx.x * 256 + threadIdx.x;
    if (e >= KH * 64) return;
    const int kh = e >> 6;
    const int L  = e & 63;
    const int n  = L & 15;
    const int q  = L >> 4;
    bf16x8 bv;
#pragma unroll
    for (int j = 0; j < 8; ++j) {
        const int d = q * 8 + j - n;          // k - n
        bv[j] = (d >= 0 && d < KW) ? f2bf(w[kh * KW + d]) : (short)0;
    }
    *reinterpret_cast<bf16x8*>(&btab[(size_t)e * 8]) = bv;
}

__global__ __launch_bounds__(256, 4)
void conv2d_mfma(const float* __restrict__ x,
                 const short* __restrict__ btab,
                 const float* __restrict__ bias,
                 float* __restrict__ out) {
    __shared__ short lds[NSH];

    const int tid = threadIdx.x;
    const int ox0 = blockIdx.x * BX;
    const int oy0 = blockIdx.y * BY;

    // ---------------- stage x tile: 78 x 80 fp32 -> bf16 LDS ----------------
    if (ox0 + XCOLS <= WIN && oy0 + XROWS <= HIN) {
        // interior fast path: no clamps; batch-issue all loads, then convert
        float4 v[7];
#pragma unroll
        for (int i = 0; i < 7; ++i) {
            const int f = tid + 256 * i;
            if (f < NITEM) {
                const int r  = f / NB4;
                const int c4 = (f - r * NB4) * 4;
                v[i] = *reinterpret_cast<const float4*>(&x[(size_t)(oy0 + r) * WIN + ox0 + c4]);
            }
        }
#pragma unroll
        for (int i = 0; i < 7; ++i) {
            const int f = tid + 256 * i;
            if (f < NITEM) {
                const int r  = f / NB4;
                const int c4 = (f - r * NB4) * 4;
                short4 s;
                s.x = f2bf(v[i].x); s.y = f2bf(v[i].y);
                s.z = f2bf(v[i].z); s.w = f2bf(v[i].w);
                *reinterpret_cast<short4*>(&lds[r * LDSW + c4]) = s;   // ds_write_b64
            }
        }
    } else {
        // edge blocks (bx==63 or by==63): clamped per-item path
        for (int f = tid; f < NITEM; f += 256) {
            const int r  = f / NB4;
            const int c4 = (f - r * NB4) * 4;
            int gy = oy0 + r;
            if (gy > HIN - 1) gy = HIN - 1;   // clamped rows feed only masked outputs
            const int gx = ox0 + c4;
            float4 v;
            if (gx + 3 <= WIN - 1) {
                v = *reinterpret_cast<const float4*>(&x[(size_t)gy * WIN + gx]);
            } else {
                const float* row = &x[(size_t)gy * WIN];
                const int x0 = (gx + 0 > WIN - 1) ? WIN - 1 : gx + 0;
                const int x1 = (gx + 1 > WIN - 1) ? WIN - 1 : gx + 1;
                const int x2 = (gx + 2 > WIN - 1) ? WIN - 1 : gx + 2;
                const int x3 = (gx + 3 > WIN - 1) ? WIN - 1 : gx + 3;
                v = make_float4(row[x0], row[x1], row[x2], row[x3]);
            }
            short4 s;
            s.x = f2bf(v.x); s.y = f2bf(v.y); s.z = f2bf(v.z); s.w = f2bf(v.w);
            *reinterpret_cast<short4*>(&lds[r * LDSW + c4]) = s;
        }
    }
    __syncthreads();

    // ---------------- compute: 15 kh x 4 x-tiles of 16x16 MFMA ----------------
    const int lane = tid & 63;
    const int wv   = tid >> 6;        // wave id 0..3 -> output rows [16*wv, +16)
    const int m    = lane & 15;       // A-row (and D-col) index
    const int q    = lane >> 4;       // quad

    f32x4 acc[4];
#pragma unroll
    for (int t = 0; t < 4; ++t) acc[t] = (f32x4){0.f, 0.f, 0.f, 0.f};

    // A-frag base: row (16*wv + m), col q*8 + t*16 (imm-friendly offsets)
    const short*  abase = &lds[(wv * 16 + m) * LDSW + q * 8];
    const bf16x8* bt    = reinterpret_cast<const bf16x8*>(btab) + lane;

    // initial fragments (kh = 0): one full ds_read_b128 per t
    bf16x8 f0 = *reinterpret_cast<const bf16x8*>(abase + 0 * 16);
    bf16x8 f1 = *reinterpret_cast<const bf16x8*>(abase + 1 * 16);
    bf16x8 f2 = *reinterpret_cast<const bf16x8*>(abase + 2 * 16);
    bf16x8 f3 = *reinterpret_cast<const bf16x8*>(abase + 3 * 16);

#pragma unroll
    for (int kh = 0; kh < KH; ++kh) {
        if (kh) {
            // slide the A window down one row: lane m takes lane m+1's frag
            f0 = rot_up(f0);
            f1 = rot_up(f1);
            f2 = rot_up(f2);
            f3 = rot_up(f3);
            if (m == 15) {   // boundary lanes fetch the newly-exposed row
                f0 = *reinterpret_cast<const bf16x8*>(abase + kh * LDSW + 0 * 16);
                f1 = *reinterpret_cast<const bf16x8*>(abase + kh * LDSW + 1 * 16);
                f2 = *reinterpret_cast<const bf16x8*>(abase + kh * LDSW + 2 * 16);
                f3 = *reinterpret_cast<const bf16x8*>(abase + kh * LDSW + 3 * 16);
            }
        }
        const bf16x8 b = bt[kh * 64];   // global dwordx4, L1-hot (15 KB table)
        acc[0] = __builtin_amdgcn_mfma_f32_16x16x32_bf16(f0, b, acc[0], 0, 0, 0);
        acc[1] = __builtin_amdgcn_mfma_f32_16x16x32_bf16(f1, b, acc[1], 0, 0, 0);
        acc[2] = __builtin_amdgcn_mfma_f32_16x16x32_bf16(f2, b, acc[2], 0, 0, 0);
        acc[3] = __builtin_amdgcn_mfma_f32_16x16x32_bf16(f3, b, acc[3], 0, 0, 0);
    }

    // ---------------- epilogue: D layout col=lane&15, row=q*4+reg ----------------
    const float b0 = bias[0];
    const int row0 = oy0 + wv * 16 + q * 4;
#pragma unroll
    for (int t = 0; t < 4; ++t) {
        const int col = ox0 + t * 16 + m;
        if (col < OW) {
            const f32x4 a = (t == 0) ? acc[0] : (t == 1) ? acc[1] : (t == 2) ? acc[2] : acc[3];
#pragma unroll
            for (int r = 0; r < 4; ++r) {
                const int row = row0 + r;
                if (row < OH)
                    out[(size_t)row * OW + col] = a[r] + b0;
            }
        }
    }
}

extern "C" void kernel_launch(void* const* d_in, const int* in_sizes, int n_in,
                              void* d_out, int out_size, void* d_ws, size_t ws_size,
                              hipStream_t stream) {
    const float* x    = (const float*)d_in[0];
    const float* w    = (const float*)d_in[1];
    const float* bias = (const float*)d_in[2];
    float* out        = (float*)d_out;
    short* btab       = (short*)d_ws;   // 15*64*8 shorts = 15360 B

    conv2d_btab<<<dim3((KH * 64 + 255) / 256), dim3(256), 0, stream>>>(w, btab);

    dim3 grid((OW + BX - 1) / BX, (OH + BY - 1) / BY);  // 64 x 64
    dim3 block(256);
    conv2d_mfma<<<grid, block, 0, stream>>>(x, btab, bias, out);
}

// Round 10
// 136.927 us; speedup vs baseline: 1.0533x; 1.0046x over previous
//
#include <hip/hip_runtime.h>

// Conv2D 15x15 valid, 4096^2 fp32 -> 4082^2 fp32, via bf16 MFMA Toeplitz-band.
//
// R9b: RESUBMIT of R9 (round 9 was an infra failure -- container died twice,
// no kernel signal). CONTIGUOUS-STORE EPILOGUE (LDS transpose, dwordx2),
// R1 frame otherwise.
//
// Evidence: six structurally different kernels (R1/R2/R4/R5/R7/R8) all pin at
// dur ~= hbm_bytes / 2.4 TB/s with every SQ pipe <40% -- memory-path
// throughput-bound, and bytes are already sub-compulsory (L3 absorbs input
// re-reads; WRITE ~= output size). The ONLY never-varied subsystem is the
// store path: 16 scalar dword stores/thread, each wave-instr scattering 4
// disjoint 64B segments over 4 rows, rows misaligned to 128B lines (stride
// 16328 B == 72 mod 128). Writes = 58% of traffic. Fix: per wave, dump the
// 16x64 acc tile to wave-private LDS (stride 65 = conflict-free), read back
// linearly, store 8x dwordx2/thread -- each wave-instr one 512 B contiguous
// span (8B-aligned: OW even, ox0 even). Edge blocks (3%) keep scalar path.
//
// Falsified ledger (us/dispatch): conflicts R2; B-path R2/R4; occupancy
// R1(51%)==R4(29%)==50us; barrier R5; stage-pipeline R7; LDS A-latency R8.
// If this is flat too -> declare pattern-roofline (124 MB @ 2.4 TB/s).

#define HIN 4096
#define WIN 4096
#define KH 15
#define KW 15
#define OH (HIN - KH + 1)  // 4082
#define OW (WIN - KW + 1)  // 4082

#define BX 64
#define BY 64
#define XROWS (BY + KH - 1)     // 78 staged input rows
#define XCOLS 80                // staged input cols (64 + 14, padded to 80)
#define LDSW 88                 // bf16 row stride (176 B -> bank skew 12 dwords)
#define NSH (XROWS * LDSW)      // 6864 shorts = 13728 B x-tile
#define NB4 (XCOLS / 4)         // 20 float4 per staged row
#define NITEM (XROWS * NB4)     // 1560 staging items per block
#define FSTRIDE 65              // fp32 epilogue row stride (conflict-free)
#define NFL (4 * 16 * FSTRIDE)  // 4160 floats = 16640 B total LDS (> x-tile)

typedef short bf16x8 __attribute__((ext_vector_type(8)));
typedef float f32x4  __attribute__((ext_vector_type(4)));

static __device__ inline short f2bf(float f) {  // fp32 -> bf16 RNE
    unsigned u = __float_as_uint(f);
    u += 0x7fffu + ((u >> 16) & 1u);
    return (short)(u >> 16);
}

// ---- prep: build B-fragment table (15 kh x 64 lanes x bf16x8) once in ws ----
// 16x16x32 B-operand layout: lane L holds B[k=(L>>4)*8+j][n=L&15], j=0..7,
// with B[k][n] = w[kh][k-n] (0 outside band).
__global__ void conv2d_btab(const float* __restrict__ w, short* __restrict__ btab) {
    const int e = blockIdx.x * 256 + threadIdx.x;
    if (e >= KH * 64) return;
    const int kh = e >> 6;
    const int L  = e & 63;
    const int n  = L & 15;
    const int q  = L >> 4;
    bf16x8 bv;
#pragma unroll
    for (int j = 0; j < 8; ++j) {
        const int d = q * 8 + j - n;          // k - n
        bv[j] = (d >= 0 && d < KW) ? f2bf(w[kh * KW + d]) : (short)0;
    }
    *reinterpret_cast<bf16x8*>(&btab[(size_t)e * 8]) = bv;
}

__global__ __launch_bounds__(256, 4)
void conv2d_mfma(const float* __restrict__ x,
                 const short* __restrict__ btab,
                 const float* __restrict__ bias,
                 float* __restrict__ out) {
    __shared__ float ldsf[NFL];                       // 16640 B
    short* lds = reinterpret_cast<short*>(ldsf);      // x-tile alias (13728 B)

    const int tid = threadIdx.x;
    const int ox0 = blockIdx.x * BX;
    const int oy0 = blockIdx.y * BY;
    const bool interior = (ox0 + XCOLS <= WIN) && (oy0 + XROWS <= HIN);  // bx<63 && by<63

    // ---------------- stage x tile: 78 x 80 fp32 -> bf16 LDS ----------------
    if (interior) {
        // interior fast path: no clamps; batch-issue all loads, then convert
        float4 v[7];
#pragma unroll
        for (int i = 0; i < 7; ++i) {
            const int f = tid + 256 * i;
            if (f < NITEM) {
                const int r  = f / NB4;
                const int c4 = (f - r * NB4) * 4;
                v[i] = *reinterpret_cast<const float4*>(&x[(size_t)(oy0 + r) * WIN + ox0 + c4]);
            }
        }
#pragma unroll
        for (int i = 0; i < 7; ++i) {
            const int f = tid + 256 * i;
            if (f < NITEM) {
                const int r  = f / NB4;
                const int c4 = (f - r * NB4) * 4;
                short4 s;
                s.x = f2bf(v[i].x); s.y = f2bf(v[i].y);
                s.z = f2bf(v[i].z); s.w = f2bf(v[i].w);
                *reinterpret_cast<short4*>(&lds[r * LDSW + c4]) = s;   // ds_write_b64
            }
        }
    } else {
        // edge blocks (bx==63 or by==63): clamped per-item path
        for (int f = tid; f < NITEM; f += 256) {
            const int r  = f / NB4;
            const int c4 = (f - r * NB4) * 4;
            int gy = oy0 + r;
            if (gy > HIN - 1) gy = HIN - 1;   // clamped rows feed only masked outputs
            const int gx = ox0 + c4;
            float4 v;
            if (gx + 3 <= WIN - 1) {
                v = *reinterpret_cast<const float4*>(&x[(size_t)gy * WIN + gx]);
            } else {
                const float* row = &x[(size_t)gy * WIN];
                const int x0 = (gx + 0 > WIN - 1) ? WIN - 1 : gx + 0;
                const int x1 = (gx + 1 > WIN - 1) ? WIN - 1 : gx + 1;
                const int x2 = (gx + 2 > WIN - 1) ? WIN - 1 : gx + 2;
                const int x3 = (gx + 3 > WIN - 1) ? WIN - 1 : gx + 3;
                v = make_float4(row[x0], row[x1], row[x2], row[x3]);
            }
            short4 s;
            s.x = f2bf(v.x); s.y = f2bf(v.y); s.z = f2bf(v.z); s.w = f2bf(v.w);
            *reinterpret_cast<short4*>(&lds[r * LDSW + c4]) = s;
        }
    }
    __syncthreads();

    // ---------------- compute: 15 kh x 4 x-tiles of 16x16 MFMA ----------------
    const int lane = tid & 63;
    const int wv   = tid >> 6;        // wave id 0..3 -> output rows [16*wv, +16)
    const int m    = lane & 15;       // A-row (and D-col) index
    const int q    = lane >> 4;       // quad

    f32x4 acc[4];
#pragma unroll
    for (int t = 0; t < 4; ++t) acc[t] = (f32x4){0.f, 0.f, 0.f, 0.f};

    // A-frag base: row (16*wv + m), col q*8 + t*16 (imm-friendly offsets)
    const short*  abase = &lds[(wv * 16 + m) * LDSW + q * 8];
    const bf16x8* bt    = reinterpret_cast<const bf16x8*>(btab) + lane;
#pragma unroll
    for (int kh = 0; kh < KH; ++kh) {
        const bf16x8 b = bt[kh * 64];   // global dwordx4, L1-hot (15 KB table)
#pragma unroll
        for (int t = 0; t < 4; ++t) {
            const bf16x8 a =
                *reinterpret_cast<const bf16x8*>(abase + kh * LDSW + t * 16);  // ds_read_b128
            acc[t] = __builtin_amdgcn_mfma_f32_16x16x32_bf16(a, b, acc[t], 0, 0, 0);
        }
    }

    // ------------- epilogue: D layout col=lane&15, row=q*4+reg -------------
    const float b0 = bias[0];
    if (interior) {
        // contiguous-store path: acc -> wave-private LDS (stride 65, conflict-
        // free) -> 8x dwordx2/thread, each wave-instr one 512 B contiguous span.
        __syncthreads();   // all waves done reading the x-tile alias
        float* wbuf = &ldsf[wv * 16 * FSTRIDE];
#pragma unroll
        for (int t = 0; t < 4; ++t) {
#pragma unroll
            for (int r = 0; r < 4; ++r)
                wbuf[(q * 4 + r) * FSTRIDE + t * 16 + m] = acc[t][r] + b0;  // ds_write_b32
        }
        // wave-private readback (same wave wrote it -> lgkmcnt dependency only)
        const size_t obase = (size_t)(oy0 + wv * 16) * OW + ox0;
#pragma unroll
        for (int i = 0; i < 8; ++i) {
            const int g  = lane + 64 * i;
            const int rl = g >> 5;          // local row 0..15
            const int c2 = g & 31;          // float2 index within row
            const float2 val = *reinterpret_cast<const float2*>(&wbuf[rl * FSTRIDE + c2 * 2]);
            *reinterpret_cast<float2*>(&out[obase + (size_t)rl * OW + c2 * 2]) = val;
        }
    } else {
        // edge blocks: proven scalar path with bounds masks
        const int row0 = oy0 + wv * 16 + q * 4;
#pragma unroll
        for (int t = 0; t < 4; ++t) {
            const int col = ox0 + t * 16 + m;
            if (col < OW) {
#pragma unroll
                for (int r = 0; r < 4; ++r) {
                    const int row = row0 + r;
                    if (row < OH)
                        out[(size_t)row * OW + col] = acc[t][r] + b0;
                }
            }
        }
    }
}

extern "C" void kernel_launch(void* const* d_in, const int* in_sizes, int n_in,
                              void* d_out, int out_size, void* d_ws, size_t ws_size,
                              hipStream_t stream) {
    const float* x    = (const float*)d_in[0];
    const float* w    = (const float*)d_in[1];
    const float* bias = (const float*)d_in[2];
    float* out        = (float*)d_out;
    short* btab       = (short*)d_ws;   // 15*64*8 shorts = 15360 B

    conv2d_btab<<<dim3((KH * 64 + 255) / 256), dim3(256), 0, stream>>>(w, btab);

    dim3 grid((OW + BX - 1) / BX, (OH + BY - 1) / BY);  // 64 x 64
    dim3 block(256);
    conv2d_mfma<<<grid, block, 0, stream>>>(x, btab, bias, out);
}